// Round 11
// baseline (144.325 us; speedup 1.0000x reference)
//
#include <hip/hip_runtime.h>
#include <hip/hip_bf16.h>

// Problem constants (reference: B=2, S=2048, D=1024, H=16, HD=64)
constexpr int Bb = 2, Ss = 2048, Dd = 1024, Hh = 16, HD = 64;
constexpr int Mrows = Bb * Ss;                 // 4096
constexpr float QSCALE = 0.125f * 1.44269504088896f;  // 1/sqrt(HD) * log2(e), folded into Q
constexpr size_t CTX_ELEMS = (size_t)Bb * Hh * Ss * HD;   // 4194304

typedef __attribute__((ext_vector_type(8)))  short        short8;
typedef __attribute__((ext_vector_type(4)))  float        floatx4;
typedef __attribute__((ext_vector_type(16))) float        floatx16;
typedef __attribute__((ext_vector_type(4)))  unsigned int uintx4;
typedef __attribute__((ext_vector_type(8)))  __bf16       bf16x8;

#define DEVI __device__ __forceinline__

DEVI unsigned short f2bf(float f) {
  union { float f; unsigned u; } x; x.f = f;
  return (unsigned short)((x.u + 0x7fffu + ((x.u >> 16) & 1u)) >> 16);   // RNE
}
DEVI float fexp2(float x) {
#if __has_builtin(__builtin_amdgcn_exp2f)
  return __builtin_amdgcn_exp2f(x);
#else
  return __expf(x * 0.6931471805599453f);
#endif
}

// workspace layout (bf16-elem units): X bf16 (3*XE) | W bf16 (3*WE) | Q|K|V^T (3*XE)
constexpr size_t XE = (size_t)Mrows * Dd;      // 4M
constexpr size_t WE = (size_t)Dd * Dd;         // 1M
constexpr size_t OFF_W = 3 * XE;
constexpr size_t OFF_O = 3 * XE + 3 * WE;

// ---------------------------------------------------------------------------
// fp32 -> bf16 conversion pass (6 tensors)  [round-9 proven path]
// ---------------------------------------------------------------------------
__global__ __launch_bounds__(256) void convert_bf16(
    const float* __restrict__ q, const float* __restrict__ k, const float* __restrict__ v,
    const float* __restrict__ wq, const float* __restrict__ wk, const float* __restrict__ wv,
    unsigned short* __restrict__ dst)
{
  const int sel = blockIdx.y;
  const float* src; size_t n, off;
  switch (sel) {
    case 0:  src = q;  n = XE; off = 0;            break;
    case 1:  src = k;  n = XE; off = XE;           break;
    case 2:  src = v;  n = XE; off = 2 * XE;       break;
    case 3:  src = wq; n = WE; off = OFF_W;        break;
    case 4:  src = wk; n = WE; off = OFF_W + WE;   break;
    default: src = wv; n = WE; off = OFF_W + 2*WE; break;
  }
  unsigned short* d = dst + off;
  const size_t stride = (size_t)gridDim.x * blockDim.x;
  for (size_t i = (size_t)blockIdx.x * blockDim.x + threadIdx.x; i < n / 8; i += stride) {
    const floatx4 a = *(const floatx4*)(src + i * 8);
    const floatx4 b = *(const floatx4*)(src + i * 8 + 4);
    short8 o;
    #pragma unroll
    for (int j = 0; j < 4; ++j) { o[j] = (short)f2bf(a[j]); o[4 + j] = (short)f2bf(b[j]); }
    *(short8*)(d + i * 8) = o;
  }
}

// ---------------------------------------------------------------------------
// GEMM epilogue (16x16 layout).
// ---------------------------------------------------------------------------
template<bool SWAP>
DEVI void store_out(floatx4 (&acc)[4][4], const float* __restrict__ bias,
                    unsigned short* __restrict__ out, float oscale,
                    int bm, int bn, int wm, int wn, int lrow, int lg)
{
  if constexpr (!SWAP) {
    #pragma unroll
    for (int ni = 0; ni < 4; ++ni) {
      const int gcol = bn * 128 + wn + ni * 16 + lrow;
      const float bval = bias[gcol];
      const int h = gcol >> 6, hd = gcol & 63;
      #pragma unroll
      for (int mi = 0; mi < 4; ++mi)
        #pragma unroll
        for (int r = 0; r < 4; ++r) {
          const int grow = bm * 128 + wm + mi * 16 + lg * 4 + r;   // = b*S + s
          const int b = grow >> 11, s = grow & 2047;
          out[(((size_t)(b * Hh + h) * Ss + s) << 6) + hd] = f2bf((acc[mi][ni][r] + bval) * oscale);
        }
    }
  } else {
    #pragma unroll
    for (int ni = 0; ni < 4; ++ni)
      #pragma unroll
      for (int r = 0; r < 4; ++r) {
        const int n = bn * 128 + wn + ni * 16 + lg * 4 + r;
        const float bval = bias[n];
        #pragma unroll
        for (int mi = 0; mi < 4; ++mi) {
          const int m = bm * 128 + wm + mi * 16 + lrow;
          out[(size_t)n * Mrows + m] = f2bf(acc[mi][ni][r] + bval);
        }
      }
  }
}

// ---------------------------------------------------------------------------
// bf16 GEMM core [round-9 proven]: global_load_lds(16B), BK=64, XOR-swizzled.
// ---------------------------------------------------------------------------
DEVI void gload16(const unsigned short* g, unsigned short* l) {
  __builtin_amdgcn_global_load_lds(
      (const __attribute__((address_space(1))) unsigned int*)g,
      (__attribute__((address_space(3))) unsigned int*)l, 16, 0, 0);
}

template<bool SWAP>
DEVI void gemm_core_bf16(const unsigned short* __restrict__ X,
                         const unsigned short* __restrict__ W,
                         const float* __restrict__ bias,
                         unsigned short* __restrict__ out, float oscale,
                         unsigned short* As, unsigned short* Bs, int bm, int bn)
{
  const int t = threadIdx.x, wid = t >> 6, lane = t & 63;
  const int lrow = lane & 15, lg = lane >> 4;
  const int wm = (wid >> 1) * 64, wn = (wid & 1) * 64;

  const int srow = lane >> 3;
  const int gch  = (lane & 7) ^ srow;
  const unsigned short* gA = X + (size_t)(bm * 128 + wid * 32 + srow) * Dd + gch * 8;
  const unsigned short* gB = W + (size_t)(bn * 128 + wid * 32 + srow) * Dd + gch * 8;
  unsigned short* lA = As + wid * 4 * 512;
  unsigned short* lB = Bs + wid * 4 * 512;

  floatx4 acc[4][4];
  #pragma unroll
  for (int i = 0; i < 4; ++i)
    #pragma unroll
    for (int j = 0; j < 4; ++j) acc[i][j] = 0.0f;

  for (int k0 = 0; k0 < Dd; k0 += 64) {
    __syncthreads();
    #pragma unroll
    for (int j = 0; j < 4; ++j) {
      gload16(gA + (size_t)j * 8 * Dd + k0, lA + j * 512);
      gload16(gB + (size_t)j * 8 * Dd + k0, lB + j * 512);
    }
    __syncthreads();

    #pragma unroll
    for (int kf = 0; kf < 2; ++kf) {
      bf16x8 af[4], bf[4];
      #pragma unroll
      for (int mi = 0; mi < 4; ++mi) {
        const int row = wm + mi * 16 + lrow;
        const int ch  = ((kf << 2) | lg) ^ (lrow & 7);
        af[mi] = __builtin_bit_cast(bf16x8, *(const short8*)&As[row * 64 + (ch << 3)]);
      }
      #pragma unroll
      for (int ni = 0; ni < 4; ++ni) {
        const int row = wn + ni * 16 + lrow;
        const int ch  = ((kf << 2) | lg) ^ (lrow & 7);
        bf[ni] = __builtin_bit_cast(bf16x8, *(const short8*)&Bs[row * 64 + (ch << 3)]);
      }
      #pragma unroll
      for (int mi = 0; mi < 4; ++mi)
        #pragma unroll
        for (int ni = 0; ni < 4; ++ni) {
          if constexpr (SWAP)
            acc[mi][ni] = __builtin_amdgcn_mfma_f32_16x16x32_bf16(bf[ni], af[mi], acc[mi][ni], 0, 0, 0);
          else
            acc[mi][ni] = __builtin_amdgcn_mfma_f32_16x16x32_bf16(af[mi], bf[ni], acc[mi][ni], 0, 0, 0);
        }
    }
  }
  store_out<SWAP>(acc, bias, out, oscale, bm, bn, wm, wn, lrow, lg);
}

__global__ __launch_bounds__(256, 3) void qkv_gemm_bf16(
    const unsigned short* __restrict__ ws,
    const float* __restrict__ bq, const float* __restrict__ bk, const float* __restrict__ bv,
    unsigned short* __restrict__ outbase)
{
  __shared__ __align__(16) unsigned short As[128 * 64];
  __shared__ __align__(16) unsigned short Bs[128 * 64];

  const int id  = blockIdx.y * 256 + blockIdx.x;
  const int swz = (id & 7) * 96 + (id >> 3);
  const int sel = swz >> 8;
  const int bx  = swz & 255;
  const int bm = bx >> 3, bn = bx & 7;

  const unsigned short* X = ws + (size_t)sel * XE;
  const unsigned short* W = ws + OFF_W + (size_t)sel * WE;
  const float* bias = sel == 0 ? bq : sel == 1 ? bk : bv;
  unsigned short* out = outbase + (size_t)sel * XE;

  if (sel == 2) gemm_core_bf16<true >(X, W, bias, out, 1.0f,   As, Bs, bm, bn);
  else          gemm_core_bf16<false>(X, W, bias, out, sel == 0 ? QSCALE : 1.0f, As, Bs, bm, bn);
}

// ---------------------------------------------------------------------------
// Flash attention, 8-wave in-block kv-split x4, KVBLK=32.
// Block = 512 threads covering 64 q-rows: wave (kq,wid), kq in [0,4) owns kv
// quarter [kq*512, kq*512+512), wid in {0,1} owns q-subtile of 32 rows.
// 1024 blocks -> 8192 waves; LDS 49 KB -> 3 blocks/CU -> 24 waves/CU.
// K single-buffered per quarter (staged mid-tile after a 2nd barrier, lands
// under PV); V double-buffered [64hd][32kv] (4-chunk XOR, accept 4-way on the
// 4 vf reads/tile).  Epilogue combines 4 quarters via LDS overlay.
// permlane32_swap: a keeps lo lanes, a_hi <- b_lo; b_lo <- a_hi, b keeps hi.
// ---------------------------------------------------------------------------
__global__ __launch_bounds__(512, 6) void attn_fwd8(
    const unsigned short* __restrict__ Qw, const unsigned short* __restrict__ Kw,
    const unsigned short* __restrict__ Vw, float* __restrict__ out)
{
  __shared__ __align__(16) char smemRaw[50176];
  // main loop: K quarters at [0,16K), V quarters at [16K,48K)
  // epilogue overlay: ctxF 6 slots x 8KB = [0,48K); lsumQ/lsumC at 48K+
  float* ctxF  = (float*)smemRaw;
  float* lsumQ = (float*)(smemRaw + 49152);          // 6*32 floats
  float* lsumC = (float*)(smemRaw + 49152 + 768);    // 2*32 floats

  // XCD-bijective swizzle: 1024 blocks -> 128-contiguous per XCD.
  const int id  = blockIdx.y * 32 + blockIdx.x;
  const int swz = (id & 7) * 128 + (id >> 3);
  const int qb  = swz & 31, bh = swz >> 5;
  const int b   = bh >> 4, h = bh & 15;

  const int t = threadIdx.x, wid8 = t >> 6, lane = t & 63;
  const int kq = wid8 >> 1, wid = wid8 & 1;    // kv-quarter, q-subtile
  const int l31 = lane & 31, hi = lane >> 5;
  const int kvbase = kq << 9;                  // *512
  const unsigned short* Qb = Qw + (size_t)bh * (Ss * HD);
  const unsigned short* Kb = Kw + (size_t)bh * (Ss * HD);
  const unsigned short* Vg = Vw + (size_t)(h * 64) * Mrows + b * Ss;   // row=hd
  const int q0 = qb * 64 + wid * 32;

  unsigned short* Kq = (unsigned short*)(smemRaw + kq * 4096);            // 4KB, 1 buf
  unsigned short* Vq = (unsigned short*)(smemRaw + 16384 + kq * 8192);    // 2 x 4KB

  // Q B-fragments: lane holds Q[q=l31][hd = hs*16 + hi*8 + j]
  bf16x8 qf[4];
  #pragma unroll
  for (int hs = 0; hs < 4; ++hs)
    qf[hs] = __builtin_bit_cast(bf16x8,
        *(const short8*)(Qb + (size_t)(q0 + l31) * 64 + hs * 16 + hi * 8));

  floatx16 ctx[2];
  ctx[0] = 0.0f; ctx[1] = 0.0f;
  float lsumv = 0.0f;

  // K staging: tile [32 kv][64 hd], 128B rows, 8-chunk XOR; 2 waves x 2 gload16.
  const int rl = lane >> 3;                  // 0..7
  const int cs = (lane & 7) ^ rl;
  auto stageK = [&](int T) {
    const int kv0 = kvbase + T * 32;
    #pragma unroll
    for (int i = 0; i < 2; ++i) {
      const int row = wid * 16 + i * 8 + rl;
      gload16(Kb + (size_t)(kv0 + row) * 64 + cs * 8, Kq + (wid * 16 + i * 8) * 64);
    }
  };
  // V staging: tile [64 hd][32 kv], 64B rows, 4-chunk XOR; 2 waves x 2 gload16.
  const int rv = lane >> 2;                  // 0..15
  const int cv = (lane & 3) ^ (rv & 3);
  auto stageV = [&](int T) {
    const int kv0 = kvbase + T * 32;
    unsigned short* Vd = Vq + (T & 1) * 2048;
    #pragma unroll
    for (int i = 0; i < 2; ++i) {
      const int rowb = wid * 32 + i * 16;
      gload16(Vg + (size_t)(rowb + rv) * Mrows + kv0 + cv * 8, Vd + rowb * 32);
    }
  };

  stageV(0);
  stageK(0);

  for (int T = 0; T < 16; ++T) {
    __syncthreads();                         // V(T),K(T) visible; V buf (T+1)&1 free
    if (T + 1 < 16) stageV(T + 1);
    const unsigned short* Vc = Vq + (T & 1) * 2048;

    // ---- S^T = K Q^T (32 kv x 32 q) ----
    floatx16 s = 0.0f;
    __builtin_amdgcn_s_setprio(1);
    #pragma unroll
    for (int hs = 0; hs < 4; ++hs) {
      const int ch = ((hs << 1) | hi) ^ (l31 & 7);
      const bf16x8 kf = __builtin_bit_cast(bf16x8,
          *(const short8*)&Kq[l31 * 64 + (ch << 3)]);
      s = __builtin_amdgcn_mfma_f32_32x32x16_bf16(kf, qf[hs], s, 0, 0, 0);
    }
    __builtin_amdgcn_s_setprio(0);

    if (T + 1 < 16) {                        // K reads done -> overwrite under PV
      __syncthreads();
      stageK(T + 1);
    }

    // ---- softmax + pack ----
    float p[16];
    #pragma unroll
    for (int r = 0; r < 16; ++r) { p[r] = fexp2(s[r]); lsumv += p[r]; }
    unsigned int c[8];
    #pragma unroll
    for (int i = 0; i < 8; ++i)
      asm("v_cvt_pk_bf16_f32 %0, %1, %2" : "=v"(c[i]) : "v"(p[2 * i]), "v"(p[2 * i + 1]));

    // ---- PV ----
    #pragma unroll
    for (int ks2 = 0; ks2 < 2; ++ks2) {
      unsigned int w0 = c[4 * ks2 + 0], w2 = c[4 * ks2 + 2];
      unsigned int w1 = c[4 * ks2 + 1], w3 = c[4 * ks2 + 3];
      asm("v_permlane32_swap_b32 %0, %1" : "+v"(w0), "+v"(w2));
      asm("v_permlane32_swap_b32 %0, %1" : "+v"(w1), "+v"(w3));
      uintx4 paw; paw[0] = w0; paw[1] = w1; paw[2] = w2; paw[3] = w3;
      const bf16x8 pa = __builtin_bit_cast(bf16x8, paw);

      __builtin_amdgcn_s_setprio(1);
      #pragma unroll
      for (int nb = 0; nb < 2; ++nb) {
        const int r = nb * 32 + l31;
        const int ch = ((ks2 << 1) | hi) ^ (l31 & 3);
        const bf16x8 vf = __builtin_bit_cast(bf16x8,
            *(const short8*)&Vc[r * 32 + (ch << 3)]);
        ctx[nb] = __builtin_amdgcn_mfma_f32_32x32x16_bf16(pa, vf, ctx[nb], 0, 0, 0);
      }
      __builtin_amdgcn_s_setprio(0);
    }
  }

  // ---- lsum hi-half combine (within wave). Partner: sb (hi=0) / sa (hi=1).
  float sa = lsumv, sb = lsumv;
  asm("v_permlane32_swap_b32 %0, %1" : "+v"(sa), "+v"(sb));
  const float tot = lsumv + (hi ? sa : sb);   // quarter's column sum for q=q0+l31

  // ---- combine 4 quarters via LDS overlay ----
  __syncthreads();                            // all waves done with K/V LDS
  if (kq != 0) {
    const int sl = (kq - 1) * 2 + wid;
    #pragma unroll
    for (int r = 0; r < 16; ++r)
      #pragma unroll
      for (int nb = 0; nb < 2; ++nb)
        ctxF[sl * 2048 + (nb * 16 + r) * 64 + lane] = ctx[nb][r];
    if (hi == 0) lsumQ[sl * 32 + l31] = tot;
  }
  __syncthreads();
  if (kq == 0) {
    if (hi == 0)
      lsumC[wid * 32 + l31] = tot + lsumQ[wid * 32 + l31]
                                  + lsumQ[(2 + wid) * 32 + l31]
                                  + lsumQ[(4 + wid) * 32 + l31];
    #pragma unroll
    for (int r = 0; r < 16; ++r) {
      const int wr = (r & 3) + 8 * (r >> 2) + 4 * hi;
      const float inv = 1.0f / lsumC[wid * 32 + wr];
      const int qrow = q0 + wr;
      #pragma unroll
      for (int nb = 0; nb < 2; ++nb) {
        const int hd = nb * 32 + l31;
        const float val = (ctx[nb][r]
                           + ctxF[(0 + wid) * 2048 + (nb * 16 + r) * 64 + lane]
                           + ctxF[(2 + wid) * 2048 + (nb * 16 + r) * 64 + lane]
                           + ctxF[(4 + wid) * 2048 + (nb * 16 + r) * 64 + lane]) * inv;
        out[((size_t)bh * Ss + qrow) * 64 + hd] = val;                             // context
        out[CTX_ELEMS + (((size_t)(b * Ss + qrow)) << 10) + (h << 6) + hd] = val;  // attn_output
      }
    }
  }
}

// ---------------------------------------------------------------------------
extern "C" void kernel_launch(void* const* d_in, const int* in_sizes, int n_in,
                              void* d_out, int out_size, void* d_ws, size_t ws_size,
                              hipStream_t stream) {
  const float* q  = (const float*)d_in[0];
  const float* k  = (const float*)d_in[1];
  const float* v  = (const float*)d_in[2];
  const float* wq = (const float*)d_in[3];
  const float* bq = (const float*)d_in[4];
  const float* wk = (const float*)d_in[5];
  const float* bk = (const float*)d_in[6];
  const float* wv = (const float*)d_in[7];
  const float* bv = (const float*)d_in[8];
  unsigned short* ws = (unsigned short*)d_ws;
  float* out = (float*)d_out;

  convert_bf16<<<dim3(256, 6), 256, 0, stream>>>(q, k, v, wq, wk, wv, ws);
  qkv_gemm_bf16<<<dim3(256, 3), 256, 0, stream>>>(ws, bq, bk, bv, ws + OFF_O);
  attn_fwd8<<<dim3(32, 32), 512, 0, stream>>>(
      ws + OFF_O, ws + OFF_O + XE, ws + OFF_O + 2 * XE, out);
}